// Round 10
// baseline (278.432 us; speedup 1.0000x reference)
//
#include <hip/hip_runtime.h>
#include <hip/hip_fp16.h>

#define N_NODES 50000
#define F 128
#define N8 (8 * N_NODES)                            // 400000
#define LDK 136                                     // padded LDS row (fp16), 16B-mult

typedef _Float16 f16x8 __attribute__((ext_vector_type(8)));
typedef float    f32x4 __attribute__((ext_vector_type(4)));

// ---- prep: zero deg8 + transpose/convert both weight matrices ----
__global__ void k_prep(int* __restrict__ deg8,
                       const float* __restrict__ W1, const float* __restrict__ W2,
                       __half* __restrict__ Wt1, __half* __restrict__ Wt2) {
    const int b = blockIdx.x;
    if (b < 1563) {
        const int i = b * 256 + threadIdx.x;
        if (i < N8) deg8[i] = 0;
    } else {
        const float* W  = (b == 1563) ? W1 : W2;
        __half*      Wt = (b == 1563) ? Wt1 : Wt2;
        for (int i = threadIdx.x; i < F * F; i += 256) {
            const int k = i >> 7, n = i & 127;
            Wt[n * F + k] = __float2half(W[i]);     // Wt[n][k] = W[k][n]
        }
    }
}

// ---- per-region degree histogram: region r = blockIdx&7 (XCD-local atomics) ----
__global__ void k_count8(const int* __restrict__ dst, int E, int* __restrict__ deg8) {
    const int i = blockIdx.x * 256 + threadIdx.x;
    const int r = blockIdx.x & 7;
    if (i < E) atomicAdd(&deg8[r * N_NODES + dst[i]], 1);
}

// ---- deg[n] = sum_r deg8[r][n]; dinv; block partial sums for the scan ----
__global__ __launch_bounds__(1024) void k_bsumdeg(const int* __restrict__ deg8,
                                                  int* __restrict__ deg,
                                                  float* __restrict__ dinv,
                                                  int* __restrict__ partials) {
    const int i = blockIdx.x * 1024 + threadIdx.x;
    int s = 0;
    if (i < N_NODES) {
#pragma unroll
        for (int r = 0; r < 8; ++r) s += deg8[r * N_NODES + i];
        deg[i]  = s;
        dinv[i] = rsqrtf((float)(s + 1));            // +1 self loop
    }
    int v = s;
#pragma unroll
    for (int d = 1; d < 64; d <<= 1) v += __shfl_xor(v, d);
    __shared__ int ws[16];
    if ((threadIdx.x & 63) == 0) ws[threadIdx.x >> 6] = v;
    __syncthreads();
    if (threadIdx.x < 16) {
        int t = ws[threadIdx.x];
#pragma unroll
        for (int d = 1; d < 16; d <<= 1) t += __shfl_xor(t, d);
        if (threadIdx.x == 0) partials[blockIdx.x] = t;
    }
}

// ---- 1-wave in-place exclusive scan of up to 64*CH partials ----
__global__ void k_pscan(int* __restrict__ p, int count) {
    const int t  = threadIdx.x;
    const int CH = (count + 63) / 64;
    const int lo = t * CH, hi = min(lo + CH, count);
    int s = 0;
    for (int i = lo; i < hi; ++i) s += p[i];
    int inc = s;
#pragma unroll
    for (int d = 1; d < 64; d <<= 1) {
        const int u = __shfl_up(inc, d);
        if (t >= d) inc += u;
    }
    int run = inc - s;                               // exclusive prefix
    for (int i = lo; i < hi; ++i) { const int v = p[i]; p[i] = run; run += v; }
}

// ---- offs = exclusive scan of deg (+ sentinel at N_NODES) ----
__global__ __launch_bounds__(1024) void k_scanapply(const int* __restrict__ a,
                                                    const int* __restrict__ partials,
                                                    int* __restrict__ offs, int NT) {
    const int i = blockIdx.x * 1024 + threadIdx.x;
    const int d = (i < NT) ? a[i] : 0;
    const int lane = threadIdx.x & 63, wid = threadIdx.x >> 6;
    int inc = d;
#pragma unroll
    for (int dd = 1; dd < 64; dd <<= 1) {
        const int u = __shfl_up(inc, dd);
        if (lane >= dd) inc += u;
    }
    __shared__ int wsum[16], wpre[16];
    if (lane == 63) wsum[wid] = inc;
    __syncthreads();
    if (threadIdx.x < 16) {
        const int s = wsum[threadIdx.x];
        int is = s;
#pragma unroll
        for (int dd = 1; dd < 16; dd <<= 1) {
            const int u = __shfl_up(is, dd);
            if (threadIdx.x >= dd) is += u;
        }
        wpre[threadIdx.x] = is - s;
    }
    __syncthreads();
    const int ex = (inc - d) + wpre[wid] + partials[blockIdx.x];
    if (i <= NT) offs[i] = ex;
}

// ---- cur8[r][n] = offs[n] + sum_{r'<r} deg8[r'][n]  (canonical positions) ----
__global__ void k_curinit(const int* __restrict__ offs, const int* __restrict__ deg8,
                          int* __restrict__ cur8) {
    const int n = blockIdx.x * blockDim.x + threadIdx.x;
    if (n < N_NODES) {
        int o = offs[n];
#pragma unroll
        for (int r = 0; r < 8; ++r) {
            cur8[r * N_NODES + n] = o;
            o += deg8[r * N_NODES + n];
        }
    }
}

// ---- fill: XCD-local cursor atomics hand out final canonical csr slots ----
__global__ void k_fill8(const int* __restrict__ src, const int* __restrict__ dst, int E,
                        int* __restrict__ cur8, unsigned short* __restrict__ csr) {
    const int i = blockIdx.x * 256 + threadIdx.x;
    const int r = blockIdx.x & 7;                    // must match k_count8's mapping
    if (i < E) {
        const int d   = dst[i];
        const int pos = atomicAdd(&cur8[r * N_NODES + d], 1);
        csr[pos] = (unsigned short)src[i];
    }
}

// ---- MFMA GEMM: Hs(fp16) = dinv[row] * (X @ W); 512 thr, 128-row tiles ----
__global__ __launch_bounds__(512) void k_gemm(const float* __restrict__ X,
                                              const __half* __restrict__ Wt,
                                              const float* __restrict__ dinv,
                                              __half* __restrict__ Hs, int nrows) {
    __shared__ __half Xs[128 * LDK];                 // 34.8 KB
    __shared__ __half Ws[128 * LDK];                 // 34.8 KB
    const int t    = threadIdx.x;
    const int wid  = t >> 6;                         // 0..7
    const int lane = t & 63;
    const int r0   = blockIdx.x * 128;

    {   // stage Wt (fp16, n-major): 4 thr per n-row, 4 uint4 each
        const uint4* Wg = (const uint4*)Wt;          // 16 uint4 per n-row
        const int n = t >> 2, c0 = (t & 3) * 4;
        uint4* drow = (uint4*)&Ws[n * LDK];
#pragma unroll
        for (int j = 0; j < 4; ++j) drow[c0 + j] = Wg[n * 16 + c0 + j];
    }
    {   // stage X tile -> fp16: 4 thr per row, 8 float4 each
        const int xr = t >> 2, c0 = (t & 3) * 32;    // c0 in fp16/float units
        const int grow = min(r0 + xr, nrows - 1);    // clamp: garbage ok, no fault
        const float4* Xg = (const float4*)(X + (size_t)grow * F);
        __half2* xd = (__half2*)&Xs[xr * LDK + c0];
#pragma unroll
        for (int j = 0; j < 8; ++j) {
            const float4 v = Xg[c0 / 4 + j];
            xd[2 * j]     = __float22half2_rn(make_float2(v.x, v.y));
            xd[2 * j + 1] = __float22half2_rn(make_float2(v.z, v.w));
        }
    }
    __syncthreads();

    const int m  = lane & 15;
    const int kg = lane >> 4;
    f32x4 acc[8] = {};
#pragma unroll
    for (int kk = 0; kk < 4; ++kk) {
        const f16x8 a = *(const f16x8*)&Xs[(wid * 16 + m) * LDK + kk * 32 + kg * 8];
#pragma unroll
        for (int nt = 0; nt < 8; ++nt) {
            const f16x8 bfr = *(const f16x8*)&Ws[(nt * 16 + m) * LDK + kk * 32 + kg * 8];
            acc[nt] = __builtin_amdgcn_mfma_f32_16x16x32_f16(a, bfr, acc[nt], 0, 0, 0);
        }
    }
    __syncthreads();                                 // done reading Xs

    {   // epilogue: scale + pack fp16 into Xs
        const int lr0 = wid * 16 + kg * 4;           // 4 output rows per lane
#pragma unroll
        for (int r = 0; r < 4; ++r) {
            const int lr = lr0 + r;
            const float dn = dinv[min(r0 + lr, nrows - 1)];
#pragma unroll
            for (int nt = 0; nt < 8; ++nt)
                Xs[lr * LDK + nt * 16 + m] = __float2half(dn * acc[nt][r]);
        }
    }
    __syncthreads();
    {   // coalesced copy-out: 4 thr per row, 4 uint4 each
        const int row = t >> 2, c0 = (t & 3) * 4;
        const int g = r0 + row;
        if (g < nrows) {
            const uint4* srow = (const uint4*)&Xs[row * LDK];
            uint4* drow = (uint4*)(Hs + (size_t)g * F);
#pragma unroll
            for (int j = 0; j < 4; ++j) drow[c0 + j] = srow[c0 + j];
        }
    }
}

// ---- XCD-sliced node gather ----
// slice = blockIdx&3 (32 features, 64B of each Hs row). Since XCD = blockIdx&7
// (round-robin heuristic), each XCD touches ONE slice: 3.2 MB working set,
// L2-resident. 8-lane groups per node, uint2 (4 fp16) per lane per edge.
__global__ __launch_bounds__(256) void k_gather(const int* __restrict__ offsets,
                                                const unsigned short* __restrict__ csr,
                                                const __half* __restrict__ Hs,
                                                const float* __restrict__ dinv,
                                                const float* __restrict__ b,
                                                float* __restrict__ out) {
    const int slice = blockIdx.x & 3;
    const int sb    = blockIdx.x >> 2;               // slice-block id
    const int nsb   = gridDim.x >> 2;                // blocks per slice
    const int grp   = threadIdx.x >> 3;              // 0..31 node-groups
    const int l8    = threadIdx.x & 7;
    const int coff  = slice * 8 + l8;                // uint2 index within row (32/row)
    const uint2* __restrict__ Hv = (const uint2*)Hs;
    const int c0 = slice * 32 + l8 * 4;              // first float col of this lane
    float4 bb;
    bb.x = b[c0]; bb.y = b[c0 + 1]; bb.z = b[c0 + 2]; bb.w = b[c0 + 3];
    for (int n = sb * 32 + grp; n < N_NODES; n += nsb * 32) {
        const int beg = offsets[n], end = offsets[n + 1];
        float4 a0, a1, a2, a3;
        {   // self-loop message (pre-scaled)
            const uint2 raw = Hv[n * 32 + coff];
            const float2 f0 = __half22float2(*(const __half2*)&raw.x);
            const float2 f1 = __half22float2(*(const __half2*)&raw.y);
            a0 = make_float4(f0.x, f0.y, f1.x, f1.y);
        }
        a1 = make_float4(0.f, 0.f, 0.f, 0.f);
        a2 = make_float4(0.f, 0.f, 0.f, 0.f);
        a3 = make_float4(0.f, 0.f, 0.f, 0.f);
        int e = beg;
        for (; e + 3 < end; e += 4) {
            const int s0 = csr[e];
            const int s1 = csr[e + 1];
            const int s2 = csr[e + 2];
            const int s3 = csr[e + 3];
            const uint2 r0 = Hv[s0 * 32 + coff];
            const uint2 r1 = Hv[s1 * 32 + coff];
            const uint2 r2 = Hv[s2 * 32 + coff];
            const uint2 r3 = Hv[s3 * 32 + coff];
            float2 f;
            f = __half22float2(*(const __half2*)&r0.x); a0.x += f.x; a0.y += f.y;
            f = __half22float2(*(const __half2*)&r0.y); a0.z += f.x; a0.w += f.y;
            f = __half22float2(*(const __half2*)&r1.x); a1.x += f.x; a1.y += f.y;
            f = __half22float2(*(const __half2*)&r1.y); a1.z += f.x; a1.w += f.y;
            f = __half22float2(*(const __half2*)&r2.x); a2.x += f.x; a2.y += f.y;
            f = __half22float2(*(const __half2*)&r2.y); a2.z += f.x; a2.w += f.y;
            f = __half22float2(*(const __half2*)&r3.x); a3.x += f.x; a3.y += f.y;
            f = __half22float2(*(const __half2*)&r3.y); a3.z += f.x; a3.w += f.y;
        }
        for (; e < end; ++e) {
            const uint2 r0 = Hv[csr[e] * 32 + coff];
            float2 f;
            f = __half22float2(*(const __half2*)&r0.x); a1.x += f.x; a1.y += f.y;
            f = __half22float2(*(const __half2*)&r0.y); a1.z += f.x; a1.w += f.y;
        }
        const float dn = dinv[n];
        float4 o;
        o.x = fmaxf(fmaf(dn, (a0.x + a1.x) + (a2.x + a3.x), bb.x), 0.f);
        o.y = fmaxf(fmaf(dn, (a0.y + a1.y) + (a2.y + a3.y), bb.y), 0.f);
        o.z = fmaxf(fmaf(dn, (a0.z + a1.z) + (a2.z + a3.z), bb.z), 0.f);
        o.w = fmaxf(fmaf(dn, (a0.w + a1.w) + (a2.w + a3.w), bb.w), 0.f);
        *(float4*)&out[(size_t)n * F + c0] = o;      // 128B contiguous per group
    }
}

extern "C" void kernel_launch(void* const* d_in, const int* in_sizes, int n_in,
                              void* d_out, int out_size, void* d_ws, size_t ws_size,
                              hipStream_t stream) {
    const float* x  = (const float*)d_in[0];
    const int*   ei = (const int*)  d_in[1];
    const float* W1 = (const float*)d_in[2];
    const float* b1 = (const float*)d_in[3];
    const float* W2 = (const float*)d_in[4];
    const float* b2 = (const float*)d_in[5];
    float* out = (float*)d_out;

    const int E = in_sizes[1] / 2;        // 800000
    const int* srcp = ei;                 // edge_index[0]
    const int* dstp = ei + E;             // edge_index[1]

    // ---- workspace carve-up (16B-aligned boundaries) ----
    int*            deg8 = (int*)d_ws;                    // 400000
    int*            cur8 = deg8 + N8;                     // 400000
    int*            deg  = cur8 + N8;                     // 50000
    int*            offs = deg + N_NODES;                 // 50001 (+7 pad)
    float*          dinv = (float*)(offs + N_NODES + 8);  // 50000
    int*            part = (int*)(dinv + N_NODES);        // 64
    unsigned short* csr  = (unsigned short*)(part + 64);  // E u16
    __half*         Hs   = (__half*)(csr + E);            // N*F fp16
    __half*         Wt1  = Hs + (size_t)N_NODES * F;      // F*F fp16
    __half*         Wt2  = Wt1 + F * F;                   // F*F fp16

    const int nb_e = (E + 255) / 256;                     // 3125
    const int nb_n = (N_NODES + 1023) / 1024;             // 49

    // ---- CSR build: 7 dispatches, canonical positions ----
    k_prep    <<<1565, 256, 0, stream>>>(deg8, W1, W2, Wt1, Wt2);
    k_count8  <<<nb_e, 256, 0, stream>>>(dstp, E, deg8);
    k_bsumdeg <<<nb_n, 1024, 0, stream>>>(deg8, deg, dinv, part);
    k_pscan   <<<1, 64, 0, stream>>>(part, nb_n);
    k_scanapply<<<nb_n, 1024, 0, stream>>>(deg, part, offs, N_NODES);
    k_curinit <<<(N_NODES + 255) / 256, 256, 0, stream>>>(offs, deg8, cur8);
    k_fill8   <<<nb_e, 256, 0, stream>>>(srcp, dstp, E, cur8, csr);

    const int gemm_blocks = (N_NODES + 127) / 128;        // 391

    // ---- layer 1 ----
    k_gemm  <<<gemm_blocks, 512, 0, stream>>>(x, Wt1, dinv, Hs, N_NODES);
    k_gather<<<2048, 256, 0, stream>>>(offs, csr, Hs, dinv, b1, out);

    // ---- layer 2 ----
    k_gemm  <<<gemm_blocks, 512, 0, stream>>>(out, Wt2, dinv, Hs, N_NODES);
    k_gather<<<2048, 256, 0, stream>>>(offs, csr, Hs, dinv, b2, out);
}

// Round 11
// 207.229 us; speedup vs baseline: 1.3436x; 1.3436x over previous
//
#include <hip/hip_runtime.h>
#include <hip/hip_fp16.h>

#define N_NODES 50000
#define F 128
#define RANGE 6250                                  // dst-range per owner group (8)
#define LDK 136                                     // padded LDS row (fp16), 16B-mult

typedef _Float16 f16x8 __attribute__((ext_vector_type(8)));
typedef float    f32x4 __attribute__((ext_vector_type(4)));

// ---- prep: zero deg + transpose/convert both weight matrices ----
// blocks [0,196): zero deg; block 196: Wt1; block 197: Wt2.
__global__ void k_prep(int* __restrict__ deg,
                       const float* __restrict__ W1, const float* __restrict__ W2,
                       __half* __restrict__ Wt1, __half* __restrict__ Wt2) {
    const int b = blockIdx.x;
    if (b < 196) {
        const int i = b * 256 + threadIdx.x;
        if (i < N_NODES) deg[i] = 0;
    } else {
        const float* W  = (b == 196) ? W1 : W2;
        __half*      Wt = (b == 196) ? Wt1 : Wt2;
        for (int i = threadIdx.x; i < F * F; i += 256) {
            const int k = i >> 7, n = i & 127;
            Wt[n * F + k] = __float2half(W[i]);     // Wt[n][k] = W[k][n]
        }
    }
}

// ---- range-owned degree count: group r=blockIdx&7 owns dst in [r*RANGE,..) ----
// Each group scans the whole dst array (L3-resident stream); only the owner
// group's blocks touch deg lines in its range -> no cross-group line sharing.
__global__ void k_countR(const int* __restrict__ dst, int E, int* __restrict__ deg) {
    const int r  = blockIdx.x & 7;
    const int lo = r * RANGE, hi = min(lo + RANGE, N_NODES);
    const int base   = (blockIdx.x >> 3) * 256 + threadIdx.x;
    const int stride = (gridDim.x >> 3) * 256;
    for (int i = base; i < E; i += stride) {
        const int d = dst[i];
        if (d >= lo && d < hi) atomicAdd(&deg[d], 1);
    }
}

// ---- per-block sum (1024/block) + dinv ----
__global__ __launch_bounds__(1024) void k_bsum(const int* __restrict__ deg,
                                               float* __restrict__ dinv,
                                               int* __restrict__ partials) {
    const int i = blockIdx.x * 1024 + threadIdx.x;
    int s = 0;
    if (i < N_NODES) {
        s = deg[i];
        dinv[i] = rsqrtf((float)(s + 1));            // +1 self loop
    }
    int v = s;
#pragma unroll
    for (int d = 1; d < 64; d <<= 1) v += __shfl_xor(v, d);
    __shared__ int ws[16];
    if ((threadIdx.x & 63) == 0) ws[threadIdx.x >> 6] = v;
    __syncthreads();
    if (threadIdx.x < 16) {
        int t = ws[threadIdx.x];
#pragma unroll
        for (int d = 1; d < 16; d <<= 1) t += __shfl_xor(t, d);
        if (threadIdx.x == 0) partials[blockIdx.x] = t;
    }
}

// ---- 1-wave in-place exclusive scan of partials ----
__global__ void k_pscan(int* __restrict__ p, int count) {
    const int t  = threadIdx.x;
    const int CH = (count + 63) / 64;
    const int lo = t * CH, hi = min(lo + CH, count);
    int s = 0;
    for (int i = lo; i < hi; ++i) s += p[i];
    int inc = s;
#pragma unroll
    for (int d = 1; d < 64; d <<= 1) {
        const int u = __shfl_up(inc, d);
        if (t >= d) inc += u;
    }
    int run = inc - s;                               // exclusive prefix
    for (int i = lo; i < hi; ++i) { const int v = p[i]; p[i] = run; run += v; }
}

// ---- offs = exclusive scan of deg (+ sentinel); cur = copy ----
__global__ __launch_bounds__(1024) void k_scanapply(const int* __restrict__ a,
                                                    const int* __restrict__ partials,
                                                    int* __restrict__ offs,
                                                    int* __restrict__ cur, int NT) {
    const int i = blockIdx.x * 1024 + threadIdx.x;
    const int d = (i < NT) ? a[i] : 0;
    const int lane = threadIdx.x & 63, wid = threadIdx.x >> 6;
    int inc = d;
#pragma unroll
    for (int dd = 1; dd < 64; dd <<= 1) {
        const int u = __shfl_up(inc, dd);
        if (lane >= dd) inc += u;
    }
    __shared__ int wsum[16], wpre[16];
    if (lane == 63) wsum[wid] = inc;
    __syncthreads();
    if (threadIdx.x < 16) {
        const int s = wsum[threadIdx.x];
        int is = s;
#pragma unroll
        for (int dd = 1; dd < 16; dd <<= 1) {
            const int u = __shfl_up(is, dd);
            if (threadIdx.x >= dd) is += u;
        }
        wpre[threadIdx.x] = is - s;
    }
    __syncthreads();
    const int ex = (inc - d) + wpre[wid] + partials[blockIdx.x];
    if (i <= NT) offs[i] = ex;
    if (i < NT) cur[i] = ex;
}

// ---- range-owned fill: canonical csr slots, writes stay in the owner span ----
__global__ void k_fillR(const int* __restrict__ src, const int* __restrict__ dst, int E,
                        int* __restrict__ cur, unsigned short* __restrict__ csr) {
    const int r  = blockIdx.x & 7;
    const int lo = r * RANGE, hi = min(lo + RANGE, N_NODES);
    const int base   = (blockIdx.x >> 3) * 256 + threadIdx.x;
    const int stride = (gridDim.x >> 3) * 256;
    for (int i = base; i < E; i += stride) {
        const int d = dst[i];
        const int s = src[i];                        // coalesced unconditional load
        if (d >= lo && d < hi) {
            const int pos = atomicAdd(&cur[d], 1);
            csr[pos] = (unsigned short)s;
        }
    }
}

// ---- MFMA GEMM: Hs(fp16) = dinv[row] * (X @ W); 512 thr, 128-row tiles ----
__global__ __launch_bounds__(512) void k_gemm(const float* __restrict__ X,
                                              const __half* __restrict__ Wt,
                                              const float* __restrict__ dinv,
                                              __half* __restrict__ Hs, int nrows) {
    __shared__ __half Xs[128 * LDK];                 // 34.8 KB
    __shared__ __half Ws[128 * LDK];                 // 34.8 KB
    const int t    = threadIdx.x;
    const int wid  = t >> 6;                         // 0..7
    const int lane = t & 63;
    const int r0   = blockIdx.x * 128;

    {   // stage Wt (fp16, n-major): 4 thr per n-row, 4 uint4 each
        const uint4* Wg = (const uint4*)Wt;          // 16 uint4 per n-row
        const int n = t >> 2, c0 = (t & 3) * 4;
        uint4* drow = (uint4*)&Ws[n * LDK];
#pragma unroll
        for (int j = 0; j < 4; ++j) drow[c0 + j] = Wg[n * 16 + c0 + j];
    }
    {   // stage X tile -> fp16: 4 thr per row, 8 float4 each
        const int xr = t >> 2, c0 = (t & 3) * 32;    // c0 in fp16/float units
        const int grow = min(r0 + xr, nrows - 1);    // clamp: garbage ok, no fault
        const float4* Xg = (const float4*)(X + (size_t)grow * F);
        __half2* xd = (__half2*)&Xs[xr * LDK + c0];
#pragma unroll
        for (int j = 0; j < 8; ++j) {
            const float4 v = Xg[c0 / 4 + j];
            xd[2 * j]     = __float22half2_rn(make_float2(v.x, v.y));
            xd[2 * j + 1] = __float22half2_rn(make_float2(v.z, v.w));
        }
    }
    __syncthreads();

    const int m  = lane & 15;
    const int kg = lane >> 4;
    f32x4 acc[8] = {};
#pragma unroll
    for (int kk = 0; kk < 4; ++kk) {
        const f16x8 a = *(const f16x8*)&Xs[(wid * 16 + m) * LDK + kk * 32 + kg * 8];
#pragma unroll
        for (int nt = 0; nt < 8; ++nt) {
            const f16x8 bfr = *(const f16x8*)&Ws[(nt * 16 + m) * LDK + kk * 32 + kg * 8];
            acc[nt] = __builtin_amdgcn_mfma_f32_16x16x32_f16(a, bfr, acc[nt], 0, 0, 0);
        }
    }
    __syncthreads();                                 // done reading Xs

    {   // epilogue: scale + pack fp16 into Xs
        const int lr0 = wid * 16 + kg * 4;           // 4 output rows per lane
#pragma unroll
        for (int r = 0; r < 4; ++r) {
            const int lr = lr0 + r;
            const float dn = dinv[min(r0 + lr, nrows - 1)];
#pragma unroll
            for (int nt = 0; nt < 8; ++nt)
                Xs[lr * LDK + nt * 16 + m] = __float2half(dn * acc[nt][r]);
        }
    }
    __syncthreads();
    {   // coalesced copy-out: 4 thr per row, 4 uint4 each
        const int row = t >> 2, c0 = (t & 3) * 4;
        const int g = r0 + row;
        if (g < nrows) {
            const uint4* srow = (const uint4*)&Xs[row * LDK];
            uint4* drow = (uint4*)(Hs + (size_t)g * F);
#pragma unroll
            for (int j = 0; j < 4; ++j) drow[c0 + j] = srow[c0 + j];
        }
    }
}

// ---- node gather (fp16 rows, fp32 accumulate, u16 indices) — round-8 form ----
__global__ __launch_bounds__(256) void k_gather(const int* __restrict__ offsets,
                                                const unsigned short* __restrict__ csr,
                                                const __half* __restrict__ Hs,
                                                const float* __restrict__ dinv,
                                                const float* __restrict__ b,
                                                float* __restrict__ out) {
    const int tid = blockIdx.x * blockDim.x + threadIdx.x;
    const int g   = tid >> 5;
    const int l32 = threadIdx.x & 31;
    const int ng  = (gridDim.x * blockDim.x) >> 5;
    const uint2* __restrict__ Hv = (const uint2*)Hs;
    float4* __restrict__ outv = (float4*)out;
    const float4 bb = ((const float4*)b)[l32];
    for (int n = g; n < N_NODES; n += ng) {
        const int beg = offsets[n], end = offsets[n + 1];
        float4 a0 = make_float4(0.f, 0.f, 0.f, 0.f);
        float4 a1 = make_float4(0.f, 0.f, 0.f, 0.f);
        float4 a2 = make_float4(0.f, 0.f, 0.f, 0.f);
        float4 a3 = make_float4(0.f, 0.f, 0.f, 0.f);
        {
            const uint2 raw = Hv[n * 32 + l32];
            const float2 f0 = __half22float2(*(const __half2*)&raw.x);
            const float2 f1 = __half22float2(*(const __half2*)&raw.y);
            a0.x += f0.x; a0.y += f0.y; a0.z += f1.x; a0.w += f1.y;
        }
        int e = beg;
        for (; e + 3 < end; e += 4) {
            const int s0 = csr[e];
            const int s1 = csr[e + 1];
            const int s2 = csr[e + 2];
            const int s3 = csr[e + 3];
            const uint2 r0 = Hv[s0 * 32 + l32];
            const uint2 r1 = Hv[s1 * 32 + l32];
            const uint2 r2 = Hv[s2 * 32 + l32];
            const uint2 r3 = Hv[s3 * 32 + l32];
            float2 f;
            f = __half22float2(*(const __half2*)&r0.x); a0.x += f.x; a0.y += f.y;
            f = __half22float2(*(const __half2*)&r0.y); a0.z += f.x; a0.w += f.y;
            f = __half22float2(*(const __half2*)&r1.x); a1.x += f.x; a1.y += f.y;
            f = __half22float2(*(const __half2*)&r1.y); a1.z += f.x; a1.w += f.y;
            f = __half22float2(*(const __half2*)&r2.x); a2.x += f.x; a2.y += f.y;
            f = __half22float2(*(const __half2*)&r2.y); a2.z += f.x; a2.w += f.y;
            f = __half22float2(*(const __half2*)&r3.x); a3.x += f.x; a3.y += f.y;
            f = __half22float2(*(const __half2*)&r3.y); a3.z += f.x; a3.w += f.y;
        }
        for (; e < end; ++e) {
            const uint2 r0 = Hv[csr[e] * 32 + l32];
            float2 f;
            f = __half22float2(*(const __half2*)&r0.x); a1.x += f.x; a1.y += f.y;
            f = __half22float2(*(const __half2*)&r0.y); a1.z += f.x; a1.w += f.y;
        }
        const float dn = dinv[n];
        float4 o;
        o.x = fmaxf(fmaf(dn, (a0.x + a1.x) + (a2.x + a3.x), bb.x), 0.f);
        o.y = fmaxf(fmaf(dn, (a0.y + a1.y) + (a2.y + a3.y), bb.y), 0.f);
        o.z = fmaxf(fmaf(dn, (a0.z + a1.z) + (a2.z + a3.z), bb.z), 0.f);
        o.w = fmaxf(fmaf(dn, (a0.w + a1.w) + (a2.w + a3.w), bb.w), 0.f);
        outv[n * 32 + l32] = o;
    }
}

extern "C" void kernel_launch(void* const* d_in, const int* in_sizes, int n_in,
                              void* d_out, int out_size, void* d_ws, size_t ws_size,
                              hipStream_t stream) {
    const float* x  = (const float*)d_in[0];
    const int*   ei = (const int*)  d_in[1];
    const float* W1 = (const float*)d_in[2];
    const float* b1 = (const float*)d_in[3];
    const float* W2 = (const float*)d_in[4];
    const float* b2 = (const float*)d_in[5];
    float* out = (float*)d_out;

    const int E = in_sizes[1] / 2;        // 800000
    const int* srcp = ei;                 // edge_index[0]
    const int* dstp = ei + E;             // edge_index[1]

    // ---- workspace carve-up (16B-aligned boundaries) ----
    int*            deg  = (int*)d_ws;                    // 50000
    int*            offs = deg + N_NODES;                 // 50001 (+7 pad)
    int*            cur  = offs + N_NODES + 8;            // 50000
    float*          dinv = (float*)(cur + N_NODES);       // 50000
    int*            part = (int*)(dinv + N_NODES);        // 64
    unsigned short* csr  = (unsigned short*)(part + 64);  // E u16 (1.6MB)
    __half*         Hs   = (__half*)(csr + E);            // N*F fp16 (16B-aligned)
    __half*         Wt1  = Hs + (size_t)N_NODES * F;      // F*F fp16
    __half*         Wt2  = Wt1 + F * F;                   // F*F fp16

    const int nb_n = (N_NODES + 1023) / 1024;             // 49

    // ---- CSR build: 6 dispatches, range-owned count/fill, no merge ----
    k_prep     <<<198, 256, 0, stream>>>(deg, W1, W2, Wt1, Wt2);
    k_countR   <<<2048, 256, 0, stream>>>(dstp, E, deg);
    k_bsum     <<<nb_n, 1024, 0, stream>>>(deg, dinv, part);
    k_pscan    <<<1, 64, 0, stream>>>(part, nb_n);
    k_scanapply<<<nb_n, 1024, 0, stream>>>(deg, part, offs, cur, N_NODES);
    k_fillR    <<<2048, 256, 0, stream>>>(srcp, dstp, E, cur, csr);

    const int gemm_blocks = (N_NODES + 127) / 128;        // 391

    // ---- layer 1 ----
    k_gemm  <<<gemm_blocks, 512, 0, stream>>>(x, Wt1, dinv, Hs, N_NODES);
    k_gather<<<2048, 256, 0, stream>>>(offs, csr, Hs, dinv, b1, out);

    // ---- layer 2 ----
    k_gemm  <<<gemm_blocks, 512, 0, stream>>>(out, Wt2, dinv, Hs, N_NODES);
    k_gather<<<2048, 256, 0, stream>>>(offs, csr, Hs, dinv, b2, out);
}